// Round 14
// baseline (38.099 us; speedup 1.0000x reference)
//
#include <hip/hip_runtime.h>
#include <math.h>

#define B_    256
#define K_    5
#define N_    4096
#define NPAIR (B_ * K_)     // 1280
#define NACC  69            // 4 shared Q-moments + 5 * 13 per-k moments
#define QUARTERS 4          // blocks per b; each covers N/4 = 1024 points

// ---------------------------------------------------------------------------
// f32 3x3 eigensolve helpers (validated end-to-end: absmax 0.0 in R6-R13).
// ---------------------------------------------------------------------------
__device__ inline void cross3f(const float* a, const float* b, float* c) {
  c[0] = a[1] * b[2] - a[2] * b[1];
  c[1] = a[2] * b[0] - a[0] * b[2];
  c[2] = a[0] * b[1] - a[1] * b[0];
}
__device__ inline float dot3f(const float* a, const float* b) {
  return a[0] * b[0] + a[1] * b[1] + a[2] * b[2];
}
__device__ inline void fixsign3f(float* v) {
  const float a0 = fabsf(v[0]), a1 = fabsf(v[1]), a2 = fabsf(v[2]);
  const int i = (a0 >= a1 && a0 >= a2) ? 0 : ((a1 >= a2) ? 1 : 2);
  if (v[i] < 0.f) { v[0] = -v[0]; v[1] = -v[1]; v[2] = -v[2]; }
}
__device__ inline void eigvec3f(const float A[3][3], float lam, float* v) {
  const float r0[3] = {A[0][0] - lam, A[0][1], A[0][2]};
  const float r1[3] = {A[1][0], A[1][1] - lam, A[1][2]};
  const float r2[3] = {A[2][0], A[2][1], A[2][2] - lam};
  float c01[3], c02[3], c12[3];
  cross3f(r0, r1, c01); cross3f(r0, r2, c02); cross3f(r1, r2, c12);
  const float n01 = dot3f(c01, c01), n02 = dot3f(c02, c02), n12 = dot3f(c12, c12);
  const float* best = c01; float nb = n01;
  if (n02 > nb) { best = c02; nb = n02; }
  if (n12 > nb) { best = c12; nb = n12; }
  if (nb < 1e-30f) { v[0] = 1.f; v[1] = 0.f; v[2] = 0.f; return; }
  const float inv = 1.f / sqrtf(nb);
  v[0] = best[0] * inv; v[1] = best[1] * inv; v[2] = best[2] * inv;
}

// Reproduces the reference's buggy R = Vh diag(1,1,d) U^T via
//   tr(H R) = S0*M00 + S1*M11 + d*S2*M22,  M = Vh*Vh, d = sign(det H).
__device__ inline float svd_rmsd(const float* m) {
  const float invN = 1.f / (float)N_;
  const float sP[3] = {m[0], m[1], m[2]};
  const float sQ[3] = {m[3], m[4], m[5]};
  float H[3][3];
#pragma unroll
  for (int i = 0; i < 3; ++i)
#pragma unroll
    for (int j = 0; j < 3; ++j)
      H[i][j] = m[8 + 3 * i + j] - sP[i] * sQ[j] * invN;

  const float Sp = m[6] - dot3f(sP, sP) * invN;
  const float Sq = m[7] - dot3f(sQ, sQ) * invN;

  // A = H^T H (symmetric PSD)
  float A[3][3];
#pragma unroll
  for (int i = 0; i < 3; ++i)
#pragma unroll
    for (int j = 0; j < 3; ++j)
      A[i][j] = H[0][i] * H[0][j] + H[1][i] * H[1][j] + H[2][i] * H[2][j];

  float lam[3];
  float V[3][3];  // columns = eigenvectors
  const float q = (A[0][0] + A[1][1] + A[2][2]) * (1.f / 3.f);
  const float p1 = A[0][1] * A[0][1] + A[0][2] * A[0][2] + A[1][2] * A[1][2];
  const float p2 = (A[0][0] - q) * (A[0][0] - q) +
                   (A[1][1] - q) * (A[1][1] - q) +
                   (A[2][2] - q) * (A[2][2] - q) + 2.f * p1;
  if (p2 < 1e-20f) {
    lam[0] = lam[1] = lam[2] = q;
#pragma unroll
    for (int i = 0; i < 3; ++i)
#pragma unroll
      for (int j = 0; j < 3; ++j) V[i][j] = (i == j) ? 1.f : 0.f;
  } else {
    const float p = sqrtf(p2 * (1.f / 6.f));
    const float invp = 1.f / p;
    float Bm[3][3];
#pragma unroll
    for (int i = 0; i < 3; ++i)
#pragma unroll
      for (int j = 0; j < 3; ++j)
        Bm[i][j] = (A[i][j] - ((i == j) ? q : 0.f)) * invp;
    const float detB =
        Bm[0][0] * (Bm[1][1] * Bm[2][2] - Bm[1][2] * Bm[2][1]) -
        Bm[0][1] * (Bm[1][0] * Bm[2][2] - Bm[1][2] * Bm[2][0]) +
        Bm[0][2] * (Bm[1][0] * Bm[2][1] - Bm[1][1] * Bm[2][0]);
    float r = detB * 0.5f;
    r = fminf(1.f, fmaxf(-1.f, r));
    const float phi = acosf(r) * (1.f / 3.f);
    lam[0] = q + 2.f * p * cosf(phi);
    lam[2] = q + 2.f * p * cosf(phi + 2.0943951023931953f);  // +2pi/3
    lam[1] = 3.f * q - lam[0] - lam[2];

    float v1[3], v2[3], v3[3];
    eigvec3f(A, lam[0], v1);
    eigvec3f(A, lam[1], v2);
    // orthogonalize v2 against v1
    const float d12 = dot3f(v1, v2);
    v2[0] -= d12 * v1[0]; v2[1] -= d12 * v1[1]; v2[2] -= d12 * v1[2];
    float n2 = dot3f(v2, v2);
    if (n2 < 1e-12f) {
      const float a0 = fabsf(v1[0]), a1f = fabsf(v1[1]), a2f = fabsf(v1[2]);
      int ax = (a0 <= a1f && a0 <= a2f) ? 0 : ((a1f <= a2f) ? 1 : 2);
      float e[3] = {0.f, 0.f, 0.f};
      e[ax] = 1.f;
      const float de = dot3f(v1, e);
      v2[0] = e[0] - de * v1[0]; v2[1] = e[1] - de * v1[1]; v2[2] = e[2] - de * v1[2];
      n2 = dot3f(v2, v2);
    }
    const float invn2 = 1.f / sqrtf(n2);
    v2[0] *= invn2; v2[1] *= invn2; v2[2] *= invn2;

    fixsign3f(v1);
    fixsign3f(v2);
    cross3f(v1, v2, v3);
#pragma unroll
    for (int i = 0; i < 3; ++i) { V[i][0] = v1[i]; V[i][1] = v2[i]; V[i][2] = v3[i]; }
  }

  const float S0 = sqrtf(fmaxf(lam[0], 0.f));
  const float S1 = sqrtf(fmaxf(lam[1], 0.f));
  const float S2 = sqrtf(fmaxf(lam[2], 0.f));

  const float detH =
      H[0][0] * (H[1][1] * H[2][2] - H[1][2] * H[2][1]) -
      H[0][1] * (H[1][0] * H[2][2] - H[1][2] * H[2][0]) +
      H[0][2] * (H[1][0] * H[2][1] - H[1][1] * H[2][0]);
  const float dsg = (detH >= 0.f) ? 1.f : -1.f;

  // M = Vh*Vh (Vh = V^T): M_ii = sum_k V[k][i] * V[i][k]
  const float M00 = V[0][0] * V[0][0] + V[1][0] * V[0][1] + V[2][0] * V[0][2];
  const float M11 = V[0][1] * V[1][0] + V[1][1] * V[1][1] + V[2][1] * V[1][2];
  const float M22 = V[0][2] * V[2][0] + V[1][2] * V[2][1] + V[2][2] * V[2][2];

  const float T = S0 * M00 + S1 * M11 + dsg * S2 * M22;
  const float mse = (Sp + Sq - 2.f * T) * (1.f / (3.f * (float)N_));
  return sqrtf(mse + 1e-8f);
}

// ---------------------------------------------------------------------------
// Kernel 1: k-batched partials, 4th (final) implementation cell of the
// Q-dedupe lever: occupancy (4 blocks/b -> 3+ blocks/CU at LB(256,3)) AND
// all 18 float4 loads issued up-front (full MLP, no barriers until the end)
// AND a single 69-value butterfly per block. Apparent vector traffic:
// preds 62.9 MB + target 12.6 MB = 75.5 MB (vs R8's 125.8 MB).
// Failed cells (do not revisit): R10 = 1 blk/CU starvation; R11 = sequential
// per-k load groups (3-deep MLP); R12 = barrier-chopped per-k reduces.
// Output: partial[idx][69], idx = b*4 + quarter.
// ---------------------------------------------------------------------------
__global__ __launch_bounds__(256, 3) void kabsch_partial(
    const float* __restrict__ preds, const float* __restrict__ target,
    float* __restrict__ partial) {
  const int idx = blockIdx.x;          // 0..1023
  const int b = idx >> 2;
  const int quarter = idx & 3;
  const int tid = threadIdx.x;         // 0..255
  const int c = quarter * 256 + tid;   // chunk 0..1023 (4 points each)

  const float4* __restrict__ Q4 =
      reinterpret_cast<const float4*>(target) + (size_t)b * (N_ * 3 / 4);
  const float4* __restrict__ P4 =
      reinterpret_cast<const float4*>(preds) + (size_t)b * K_ * (N_ * 3 / 4);

  // ---- issue ALL loads up-front: 3 Q + 15 P independent float4 ----
  const float4 q0 = Q4[3 * c + 0], q1 = Q4[3 * c + 1], q2 = Q4[3 * c + 2];
  float4 pf[15];
#pragma unroll
  for (int k = 0; k < K_; ++k) {
    const float4* Pk = P4 + (size_t)k * (N_ * 3 / 4);
    pf[3 * k + 0] = Pk[3 * c + 0];
    pf[3 * k + 1] = Pk[3 * c + 1];
    pf[3 * k + 2] = Pk[3 * c + 2];
  }

  float acc[NACC];
#pragma unroll
  for (int i = 0; i < NACC; ++i) acc[i] = 0.f;

  const float qq[4][3] = {{q0.x, q0.y, q0.z},
                          {q0.w, q1.x, q1.y},
                          {q1.z, q1.w, q2.x},
                          {q2.y, q2.z, q2.w}};
#pragma unroll
  for (int m = 0; m < 4; ++m) {
    const float qx = qq[m][0], qy = qq[m][1], qz = qq[m][2];
    acc[0] += qx; acc[1] += qy; acc[2] += qz;
    acc[3] = fmaf(qx, qx, fmaf(qy, qy, fmaf(qz, qz, acc[3])));
  }

#pragma unroll
  for (int k = 0; k < K_; ++k) {
    const float4 a0 = pf[3 * k + 0], a1 = pf[3 * k + 1], a2 = pf[3 * k + 2];
    const float pp[4][3] = {{a0.x, a0.y, a0.z},
                            {a0.w, a1.x, a1.y},
                            {a1.z, a1.w, a2.x},
                            {a2.y, a2.z, a2.w}};
    const int o = 4 + 13 * k;
#pragma unroll
    for (int m = 0; m < 4; ++m) {
      const float px = pp[m][0], py = pp[m][1], pz = pp[m][2];
      const float qx = qq[m][0], qy = qq[m][1], qz = qq[m][2];
      acc[o + 0] += px; acc[o + 1] += py; acc[o + 2] += pz;
      acc[o + 3] = fmaf(px, px, fmaf(py, py, fmaf(pz, pz, acc[o + 3])));
      acc[o + 4]  = fmaf(px, qx, acc[o + 4]);
      acc[o + 5]  = fmaf(px, qy, acc[o + 5]);
      acc[o + 6]  = fmaf(px, qz, acc[o + 6]);
      acc[o + 7]  = fmaf(py, qx, acc[o + 7]);
      acc[o + 8]  = fmaf(py, qy, acc[o + 8]);
      acc[o + 9]  = fmaf(py, qz, acc[o + 9]);
      acc[o + 10] = fmaf(pz, qx, acc[o + 10]);
      acc[o + 11] = fmaf(pz, qy, acc[o + 11]);
      acc[o + 12] = fmaf(pz, qz, acc[o + 12]);
    }
  }

  // ---- single butterfly over all 69, then one LDS fold ----
#pragma unroll
  for (int off = 32; off > 0; off >>= 1) {
#pragma unroll
    for (int i = 0; i < NACC; ++i) acc[i] += __shfl_down(acc[i], off, 64);
  }

  __shared__ float red[4][NACC];
  const int lane = tid & 63, wid = tid >> 6;
  if (lane == 0) {
#pragma unroll
    for (int i = 0; i < NACC; ++i) red[wid][i] = acc[i];
  }
  __syncthreads();
  if (tid < NACC) {
    partial[(size_t)idx * NACC + tid] =
        red[0][tid] + red[1][tid] + red[2][tid] + red[3][tid];
  }
}

// ---------------------------------------------------------------------------
// Kernel 2: combine 4 partials per (b,k) in fixed order (deterministic),
// run the 1280 f32 eigensolves fully parallel. Grid 5 x 256: k = blockIdx,
// b = threadIdx. rmsd layout idx = k*256 + b.
// ---------------------------------------------------------------------------
__global__ __launch_bounds__(256) void kabsch_svd(
    const float* __restrict__ partial, float* __restrict__ rmsd) {
  const int b = threadIdx.x;
  const int k = blockIdx.x;
  const float* p0 = partial + (size_t)(b * 4 + 0) * NACC;
  const float* p1 = partial + (size_t)(b * 4 + 1) * NACC;
  const float* p2 = partial + (size_t)(b * 4 + 2) * NACC;
  const float* p3 = partial + (size_t)(b * 4 + 3) * NACC;

  const int o = 4 + 13 * k;
  float m[17];
#pragma unroll
  for (int i = 0; i < 3; ++i)          // sumP
    m[i] = p0[o + i] + p1[o + i] + p2[o + i] + p3[o + i];
#pragma unroll
  for (int i = 0; i < 3; ++i)          // sumQ
    m[3 + i] = p0[i] + p1[i] + p2[i] + p3[i];
  m[6] = p0[o + 3] + p1[o + 3] + p2[o + 3] + p3[o + 3];  // sum|p|^2
  m[7] = p0[3] + p1[3] + p2[3] + p3[3];                  // sum|q|^2
#pragma unroll
  for (int i = 0; i < 9; ++i)          // H
    m[8 + i] = p0[o + 4 + i] + p1[o + 4 + i] + p2[o + 4 + i] + p3[o + 4 + i];

  rmsd[k * 256 + b] = svd_rmsd(m);
}

// ---------------------------------------------------------------------------
// Kernel 3: min over K, mean over B -> scalar.
// ---------------------------------------------------------------------------
__global__ __launch_bounds__(256) void kabsch_final(
    const float* __restrict__ rmsd, float* __restrict__ out) {
  const int b = threadIdx.x;  // 256 threads == B_
  float mn = rmsd[b];
#pragma unroll
  for (int k = 1; k < K_; ++k) mn = fminf(mn, rmsd[k * 256 + b]);
#pragma unroll
  for (int off = 32; off > 0; off >>= 1) mn += __shfl_down(mn, off, 64);
  __shared__ float s[4];
  if ((b & 63) == 0) s[b >> 6] = mn;
  __syncthreads();
  if (b == 0) out[0] = (s[0] + s[1] + s[2] + s[3]) * (1.0f / 256.0f);
}

extern "C" void kernel_launch(void* const* d_in, const int* in_sizes, int n_in,
                              void* d_out, int out_size, void* d_ws, size_t ws_size,
                              hipStream_t stream) {
  const float* preds = (const float*)d_in[0];
  const float* target = (const float*)d_in[1];
  float* out = (float*)d_out;
  float* partial = (float*)d_ws;                       // 1024*69 floats
  float* rm = partial + (size_t)B_ * QUARTERS * NACC;  // NPAIR floats

  hipLaunchKernelGGL(kabsch_partial, dim3(B_ * QUARTERS), dim3(256), 0, stream,
                     preds, target, partial);
  hipLaunchKernelGGL(kabsch_svd, dim3(K_), dim3(256), 0, stream, partial, rm);
  hipLaunchKernelGGL(kabsch_final, dim3(1), dim3(256), 0, stream, rm, out);
}

// Round 15
// 22.074 us; speedup vs baseline: 1.7260x; 1.7260x over previous
//
#include <hip/hip_runtime.h>
#include <math.h>

#define B_    256
#define K_    5
#define N_    4096
#define NPAIR (B_ * K_)     // 1280
#define NMOM  17

// ---------------------------------------------------------------------------
// FINAL KERNEL (R8 structure; benched 22.10 us in R8 and R13).
// Budget: moments+svd ~19 us @ 6.7 TB/s apparent (125.8 MB; per-CU delivery
// ceiling = fill-kernel rate), final ~1.3 us, gap+replay ~2 us.
// Falsified (do not revisit):
//  - single-kernel last-block reduce: R4 acq-rel = L2 wb/inv storm (-27us);
//    R6 relaxed-atomic = counter RMW + store-ack holds (-14us).
//  - Q-read-once k-batching (75.5 MB): R10 (1 blk/CU starved), R11 (fat
//    69-reg state), R12 (barrier-chopped thin state), R14 (full MLP + full
//    occupancy) -- 69 live accumulators/thread serializes/spills in every
//    corner; costs exceed the ~7us traffic saving.
//  - register double-buffer prefetch: R7 neutral (20 waves/CU already hides).
// f32 eigensolve: validated absmax 0.0 across R6-R14.
// ---------------------------------------------------------------------------
__device__ inline void cross3f(const float* a, const float* b, float* c) {
  c[0] = a[1] * b[2] - a[2] * b[1];
  c[1] = a[2] * b[0] - a[0] * b[2];
  c[2] = a[0] * b[1] - a[1] * b[0];
}
__device__ inline float dot3f(const float* a, const float* b) {
  return a[0] * b[0] + a[1] * b[1] + a[2] * b[2];
}
__device__ inline void fixsign3f(float* v) {
  const float a0 = fabsf(v[0]), a1 = fabsf(v[1]), a2 = fabsf(v[2]);
  const int i = (a0 >= a1 && a0 >= a2) ? 0 : ((a1 >= a2) ? 1 : 2);
  if (v[i] < 0.f) { v[0] = -v[0]; v[1] = -v[1]; v[2] = -v[2]; }
}
__device__ inline void eigvec3f(const float A[3][3], float lam, float* v) {
  const float r0[3] = {A[0][0] - lam, A[0][1], A[0][2]};
  const float r1[3] = {A[1][0], A[1][1] - lam, A[1][2]};
  const float r2[3] = {A[2][0], A[2][1], A[2][2] - lam};
  float c01[3], c02[3], c12[3];
  cross3f(r0, r1, c01); cross3f(r0, r2, c02); cross3f(r1, r2, c12);
  const float n01 = dot3f(c01, c01), n02 = dot3f(c02, c02), n12 = dot3f(c12, c12);
  const float* best = c01; float nb = n01;
  if (n02 > nb) { best = c02; nb = n02; }
  if (n12 > nb) { best = c12; nb = n12; }
  if (nb < 1e-30f) { v[0] = 1.f; v[1] = 0.f; v[2] = 0.f; return; }
  const float inv = 1.f / sqrtf(nb);
  v[0] = best[0] * inv; v[1] = best[1] * inv; v[2] = best[2] * inv;
}

// Reproduces the reference's buggy R = Vh diag(1,1,d) U^T via
//   tr(H R) = S0*M00 + S1*M11 + d*S2*M22,  M = Vh*Vh, d = sign(det H).
__device__ inline float svd_rmsd(const float* m) {
  const float invN = 1.f / (float)N_;
  const float sP[3] = {m[0], m[1], m[2]};
  const float sQ[3] = {m[3], m[4], m[5]};
  float H[3][3];
#pragma unroll
  for (int i = 0; i < 3; ++i)
#pragma unroll
    for (int j = 0; j < 3; ++j)
      H[i][j] = m[8 + 3 * i + j] - sP[i] * sQ[j] * invN;

  const float Sp = m[6] - dot3f(sP, sP) * invN;
  const float Sq = m[7] - dot3f(sQ, sQ) * invN;

  // A = H^T H (symmetric PSD)
  float A[3][3];
#pragma unroll
  for (int i = 0; i < 3; ++i)
#pragma unroll
    for (int j = 0; j < 3; ++j)
      A[i][j] = H[0][i] * H[0][j] + H[1][i] * H[1][j] + H[2][i] * H[2][j];

  float lam[3];
  float V[3][3];  // columns = eigenvectors
  const float q = (A[0][0] + A[1][1] + A[2][2]) * (1.f / 3.f);
  const float p1 = A[0][1] * A[0][1] + A[0][2] * A[0][2] + A[1][2] * A[1][2];
  const float p2 = (A[0][0] - q) * (A[0][0] - q) +
                   (A[1][1] - q) * (A[1][1] - q) +
                   (A[2][2] - q) * (A[2][2] - q) + 2.f * p1;
  if (p2 < 1e-20f) {
    lam[0] = lam[1] = lam[2] = q;
#pragma unroll
    for (int i = 0; i < 3; ++i)
#pragma unroll
      for (int j = 0; j < 3; ++j) V[i][j] = (i == j) ? 1.f : 0.f;
  } else {
    const float p = sqrtf(p2 * (1.f / 6.f));
    const float invp = 1.f / p;
    float Bm[3][3];
#pragma unroll
    for (int i = 0; i < 3; ++i)
#pragma unroll
      for (int j = 0; j < 3; ++j)
        Bm[i][j] = (A[i][j] - ((i == j) ? q : 0.f)) * invp;
    const float detB =
        Bm[0][0] * (Bm[1][1] * Bm[2][2] - Bm[1][2] * Bm[2][1]) -
        Bm[0][1] * (Bm[1][0] * Bm[2][2] - Bm[1][2] * Bm[2][0]) +
        Bm[0][2] * (Bm[1][0] * Bm[2][1] - Bm[1][1] * Bm[2][0]);
    float r = detB * 0.5f;
    r = fminf(1.f, fmaxf(-1.f, r));
    const float phi = acosf(r) * (1.f / 3.f);
    lam[0] = q + 2.f * p * cosf(phi);
    lam[2] = q + 2.f * p * cosf(phi + 2.0943951023931953f);  // +2pi/3
    lam[1] = 3.f * q - lam[0] - lam[2];

    float v1[3], v2[3], v3[3];
    eigvec3f(A, lam[0], v1);
    eigvec3f(A, lam[1], v2);
    // orthogonalize v2 against v1
    const float d12 = dot3f(v1, v2);
    v2[0] -= d12 * v1[0]; v2[1] -= d12 * v1[1]; v2[2] -= d12 * v1[2];
    float n2 = dot3f(v2, v2);
    if (n2 < 1e-12f) {
      const float a0 = fabsf(v1[0]), a1f = fabsf(v1[1]), a2f = fabsf(v1[2]);
      int ax = (a0 <= a1f && a0 <= a2f) ? 0 : ((a1f <= a2f) ? 1 : 2);
      float e[3] = {0.f, 0.f, 0.f};
      e[ax] = 1.f;
      const float de = dot3f(v1, e);
      v2[0] = e[0] - de * v1[0]; v2[1] = e[1] - de * v1[1]; v2[2] = e[2] - de * v1[2];
      n2 = dot3f(v2, v2);
    }
    const float invn2 = 1.f / sqrtf(n2);
    v2[0] *= invn2; v2[1] *= invn2; v2[2] *= invn2;

    fixsign3f(v1);
    fixsign3f(v2);
    cross3f(v1, v2, v3);
#pragma unroll
    for (int i = 0; i < 3; ++i) { V[i][0] = v1[i]; V[i][1] = v2[i]; V[i][2] = v3[i]; }
  }

  const float S0 = sqrtf(fmaxf(lam[0], 0.f));
  const float S1 = sqrtf(fmaxf(lam[1], 0.f));
  const float S2 = sqrtf(fmaxf(lam[2], 0.f));

  const float detH =
      H[0][0] * (H[1][1] * H[2][2] - H[1][2] * H[2][1]) -
      H[0][1] * (H[1][0] * H[2][2] - H[1][2] * H[2][0]) +
      H[0][2] * (H[1][0] * H[2][1] - H[1][1] * H[2][0]);
  const float dsg = (detH >= 0.f) ? 1.f : -1.f;

  // M = Vh*Vh (Vh = V^T): M_ii = sum_k V[k][i] * V[i][k]
  const float M00 = V[0][0] * V[0][0] + V[1][0] * V[0][1] + V[2][0] * V[0][2];
  const float M11 = V[0][1] * V[1][0] + V[1][1] * V[1][1] + V[2][1] * V[1][2];
  const float M22 = V[0][2] * V[2][0] + V[1][2] * V[2][1] + V[2][2] * V[2][2];

  const float T = S0 * M00 + S1 * M11 + dsg * S2 * M22;
  const float mse = (Sp + Sq - 2.f * T) * (1.f / (3.f * (float)N_));
  return sqrtf(mse + 1e-8f);
}

// ---------------------------------------------------------------------------
// Kernel 1: per-(b,k) moments + in-block svd -> rmsd[idx], plain store.
// 1280 blocks x 256 threads = 5 blocks/CU, 20 waves/CU; 17 thin accumulators.
// Block index idx = k*256 + b keeps all K=5 blocks of a given b on one XCD
// (idx%8 == b%8) for L2-local target re-reads (R2->R3: -6.7us).
// ---------------------------------------------------------------------------
__global__ __launch_bounds__(256) void kabsch_moments_svd(
    const float* __restrict__ preds, const float* __restrict__ target,
    float* __restrict__ rmsd) {
  const int idx = blockIdx.x;         // 0..1279, idx = k*256 + b
  const int b = idx & 255;
  const int k = idx >> 8;
  const int pair_orig = b * K_ + k;   // preds memory order is [B,K,N,3]
  const int tid = threadIdx.x;

  const float4* __restrict__ P4 =
      reinterpret_cast<const float4*>(preds) + (size_t)pair_orig * (N_ * 3 / 4);
  const float4* __restrict__ Q4 =
      reinterpret_cast<const float4*>(target) + (size_t)b * (N_ * 3 / 4);

  float acc[NMOM];
#pragma unroll
  for (int i = 0; i < NMOM; ++i) acc[i] = 0.f;

  // 4096 points = 1024 chunks of 4 points (3 float4 each); 256 threads x 4
#pragma unroll
  for (int j = 0; j < 4; ++j) {
    const int c = tid + j * 256;
    const float4 a0 = P4[3 * c + 0], a1 = P4[3 * c + 1], a2 = P4[3 * c + 2];
    const float4 b0 = Q4[3 * c + 0], b1 = Q4[3 * c + 1], b2 = Q4[3 * c + 2];
    const float p[4][3] = {{a0.x, a0.y, a0.z},
                           {a0.w, a1.x, a1.y},
                           {a1.z, a1.w, a2.x},
                           {a2.y, a2.z, a2.w}};
    const float q[4][3] = {{b0.x, b0.y, b0.z},
                           {b0.w, b1.x, b1.y},
                           {b1.z, b1.w, b2.x},
                           {b2.y, b2.z, b2.w}};
#pragma unroll
    for (int m = 0; m < 4; ++m) {
      const float px = p[m][0], py = p[m][1], pz = p[m][2];
      const float qx = q[m][0], qy = q[m][1], qz = q[m][2];
      acc[0] += px; acc[1] += py; acc[2] += pz;
      acc[3] += qx; acc[4] += qy; acc[5] += qz;
      acc[6] = fmaf(px, px, fmaf(py, py, fmaf(pz, pz, acc[6])));
      acc[7] = fmaf(qx, qx, fmaf(qy, qy, fmaf(qz, qz, acc[7])));
      acc[8]  = fmaf(px, qx, acc[8]);
      acc[9]  = fmaf(px, qy, acc[9]);
      acc[10] = fmaf(px, qz, acc[10]);
      acc[11] = fmaf(py, qx, acc[11]);
      acc[12] = fmaf(py, qy, acc[12]);
      acc[13] = fmaf(py, qz, acc[13]);
      acc[14] = fmaf(pz, qx, acc[14]);
      acc[15] = fmaf(pz, qy, acc[15]);
      acc[16] = fmaf(pz, qz, acc[16]);
    }
  }

  // wave64 butterfly reduce, then cross-wave via LDS
#pragma unroll
  for (int off = 32; off > 0; off >>= 1) {
#pragma unroll
    for (int i = 0; i < NMOM; ++i) acc[i] += __shfl_down(acc[i], off, 64);
  }

  __shared__ float red[4][NMOM];
  const int lane = tid & 63, wid = tid >> 6;
  if (lane == 0) {
#pragma unroll
    for (int i = 0; i < NMOM; ++i) red[wid][i] = acc[i];
  }
  __syncthreads();

  // in-block svd tail: ~1.5k-cycle f32 chain on lane 0, plain store, done.
  if (tid == 0) {
    float m[NMOM];
#pragma unroll
    for (int i = 0; i < NMOM; ++i)
      m[i] = red[0][i] + red[1][i] + red[2][i] + red[3][i];
    rmsd[idx] = svd_rmsd(m);
  }
}

// ---------------------------------------------------------------------------
// Kernel 2: min over K, mean over B -> scalar.
// rmsd layout is idx = k*256 + b, so per-b min reads stride-256 (coalesced).
// ---------------------------------------------------------------------------
__global__ __launch_bounds__(256) void kabsch_final(
    const float* __restrict__ rmsd, float* __restrict__ out) {
  const int b = threadIdx.x;  // 256 threads == B_
  float mn = rmsd[b];
#pragma unroll
  for (int k = 1; k < K_; ++k) mn = fminf(mn, rmsd[k * 256 + b]);
#pragma unroll
  for (int off = 32; off > 0; off >>= 1) mn += __shfl_down(mn, off, 64);
  __shared__ float s[4];
  if ((b & 63) == 0) s[b >> 6] = mn;
  __syncthreads();
  if (b == 0) out[0] = (s[0] + s[1] + s[2] + s[3]) * (1.0f / 256.0f);
}

extern "C" void kernel_launch(void* const* d_in, const int* in_sizes, int n_in,
                              void* d_out, int out_size, void* d_ws, size_t ws_size,
                              hipStream_t stream) {
  const float* preds = (const float*)d_in[0];
  const float* target = (const float*)d_in[1];
  float* out = (float*)d_out;
  float* rm = (float*)d_ws;                      // NPAIR floats

  hipLaunchKernelGGL(kabsch_moments_svd, dim3(NPAIR), dim3(256), 0, stream,
                     preds, target, rm);
  hipLaunchKernelGGL(kabsch_final, dim3(1), dim3(256), 0, stream, rm, out);
}

// Round 16
// 21.818 us; speedup vs baseline: 1.7463x; 1.0117x over previous
//
#include <hip/hip_runtime.h>
#include <math.h>

#define B_    256
#define K_    5
#define N_    4096
#define NPAIR (B_ * K_)     // 1280
#define NMOM  17

// ---------------------------------------------------------------------------
// FINAL KERNEL (R8 structure; benched 22.10 us in R8 and R13).
// Budget: moments+svd ~19 us @ 6.7 TB/s apparent (125.8 MB; per-CU delivery
// ceiling = fill-kernel rate), final ~1.3 us, gap+replay ~2 us.
// Falsified (do not revisit):
//  - single-kernel last-block reduce: R4 acq-rel = L2 wb/inv storm (-27us);
//    R6 relaxed-atomic = counter RMW + store-ack holds (-14us).
//  - Q-read-once k-batching (75.5 MB): R10 (1 blk/CU starved), R11 (fat
//    69-reg state), R12 (barrier-chopped thin state), R14 (full MLP + full
//    occupancy) -- 69 live accumulators/thread serializes/spills in every
//    corner; costs exceed the ~7us traffic saving.
//  - register double-buffer prefetch: R7 neutral (20 waves/CU already hides).
// f32 eigensolve: validated absmax 0.0 across R6-R14.
// ---------------------------------------------------------------------------
__device__ inline void cross3f(const float* a, const float* b, float* c) {
  c[0] = a[1] * b[2] - a[2] * b[1];
  c[1] = a[2] * b[0] - a[0] * b[2];
  c[2] = a[0] * b[1] - a[1] * b[0];
}
__device__ inline float dot3f(const float* a, const float* b) {
  return a[0] * b[0] + a[1] * b[1] + a[2] * b[2];
}
__device__ inline void fixsign3f(float* v) {
  const float a0 = fabsf(v[0]), a1 = fabsf(v[1]), a2 = fabsf(v[2]);
  const int i = (a0 >= a1 && a0 >= a2) ? 0 : ((a1 >= a2) ? 1 : 2);
  if (v[i] < 0.f) { v[0] = -v[0]; v[1] = -v[1]; v[2] = -v[2]; }
}
__device__ inline void eigvec3f(const float A[3][3], float lam, float* v) {
  const float r0[3] = {A[0][0] - lam, A[0][1], A[0][2]};
  const float r1[3] = {A[1][0], A[1][1] - lam, A[1][2]};
  const float r2[3] = {A[2][0], A[2][1], A[2][2] - lam};
  float c01[3], c02[3], c12[3];
  cross3f(r0, r1, c01); cross3f(r0, r2, c02); cross3f(r1, r2, c12);
  const float n01 = dot3f(c01, c01), n02 = dot3f(c02, c02), n12 = dot3f(c12, c12);
  const float* best = c01; float nb = n01;
  if (n02 > nb) { best = c02; nb = n02; }
  if (n12 > nb) { best = c12; nb = n12; }
  if (nb < 1e-30f) { v[0] = 1.f; v[1] = 0.f; v[2] = 0.f; return; }
  const float inv = 1.f / sqrtf(nb);
  v[0] = best[0] * inv; v[1] = best[1] * inv; v[2] = best[2] * inv;
}

// Reproduces the reference's buggy R = Vh diag(1,1,d) U^T via
//   tr(H R) = S0*M00 + S1*M11 + d*S2*M22,  M = Vh*Vh, d = sign(det H).
__device__ inline float svd_rmsd(const float* m) {
  const float invN = 1.f / (float)N_;
  const float sP[3] = {m[0], m[1], m[2]};
  const float sQ[3] = {m[3], m[4], m[5]};
  float H[3][3];
#pragma unroll
  for (int i = 0; i < 3; ++i)
#pragma unroll
    for (int j = 0; j < 3; ++j)
      H[i][j] = m[8 + 3 * i + j] - sP[i] * sQ[j] * invN;

  const float Sp = m[6] - dot3f(sP, sP) * invN;
  const float Sq = m[7] - dot3f(sQ, sQ) * invN;

  // A = H^T H (symmetric PSD)
  float A[3][3];
#pragma unroll
  for (int i = 0; i < 3; ++i)
#pragma unroll
    for (int j = 0; j < 3; ++j)
      A[i][j] = H[0][i] * H[0][j] + H[1][i] * H[1][j] + H[2][i] * H[2][j];

  float lam[3];
  float V[3][3];  // columns = eigenvectors
  const float q = (A[0][0] + A[1][1] + A[2][2]) * (1.f / 3.f);
  const float p1 = A[0][1] * A[0][1] + A[0][2] * A[0][2] + A[1][2] * A[1][2];
  const float p2 = (A[0][0] - q) * (A[0][0] - q) +
                   (A[1][1] - q) * (A[1][1] - q) +
                   (A[2][2] - q) * (A[2][2] - q) + 2.f * p1;
  if (p2 < 1e-20f) {
    lam[0] = lam[1] = lam[2] = q;
#pragma unroll
    for (int i = 0; i < 3; ++i)
#pragma unroll
      for (int j = 0; j < 3; ++j) V[i][j] = (i == j) ? 1.f : 0.f;
  } else {
    const float p = sqrtf(p2 * (1.f / 6.f));
    const float invp = 1.f / p;
    float Bm[3][3];
#pragma unroll
    for (int i = 0; i < 3; ++i)
#pragma unroll
      for (int j = 0; j < 3; ++j)
        Bm[i][j] = (A[i][j] - ((i == j) ? q : 0.f)) * invp;
    const float detB =
        Bm[0][0] * (Bm[1][1] * Bm[2][2] - Bm[1][2] * Bm[2][1]) -
        Bm[0][1] * (Bm[1][0] * Bm[2][2] - Bm[1][2] * Bm[2][0]) +
        Bm[0][2] * (Bm[1][0] * Bm[2][1] - Bm[1][1] * Bm[2][0]);
    float r = detB * 0.5f;
    r = fminf(1.f, fmaxf(-1.f, r));
    const float phi = acosf(r) * (1.f / 3.f);
    lam[0] = q + 2.f * p * cosf(phi);
    lam[2] = q + 2.f * p * cosf(phi + 2.0943951023931953f);  // +2pi/3
    lam[1] = 3.f * q - lam[0] - lam[2];

    float v1[3], v2[3], v3[3];
    eigvec3f(A, lam[0], v1);
    eigvec3f(A, lam[1], v2);
    // orthogonalize v2 against v1
    const float d12 = dot3f(v1, v2);
    v2[0] -= d12 * v1[0]; v2[1] -= d12 * v1[1]; v2[2] -= d12 * v1[2];
    float n2 = dot3f(v2, v2);
    if (n2 < 1e-12f) {
      const float a0 = fabsf(v1[0]), a1f = fabsf(v1[1]), a2f = fabsf(v1[2]);
      int ax = (a0 <= a1f && a0 <= a2f) ? 0 : ((a1f <= a2f) ? 1 : 2);
      float e[3] = {0.f, 0.f, 0.f};
      e[ax] = 1.f;
      const float de = dot3f(v1, e);
      v2[0] = e[0] - de * v1[0]; v2[1] = e[1] - de * v1[1]; v2[2] = e[2] - de * v1[2];
      n2 = dot3f(v2, v2);
    }
    const float invn2 = 1.f / sqrtf(n2);
    v2[0] *= invn2; v2[1] *= invn2; v2[2] *= invn2;

    fixsign3f(v1);
    fixsign3f(v2);
    cross3f(v1, v2, v3);
#pragma unroll
    for (int i = 0; i < 3; ++i) { V[i][0] = v1[i]; V[i][1] = v2[i]; V[i][2] = v3[i]; }
  }

  const float S0 = sqrtf(fmaxf(lam[0], 0.f));
  const float S1 = sqrtf(fmaxf(lam[1], 0.f));
  const float S2 = sqrtf(fmaxf(lam[2], 0.f));

  const float detH =
      H[0][0] * (H[1][1] * H[2][2] - H[1][2] * H[2][1]) -
      H[0][1] * (H[1][0] * H[2][2] - H[1][2] * H[2][0]) +
      H[0][2] * (H[1][0] * H[2][1] - H[1][1] * H[2][0]);
  const float dsg = (detH >= 0.f) ? 1.f : -1.f;

  // M = Vh*Vh (Vh = V^T): M_ii = sum_k V[k][i] * V[i][k]
  const float M00 = V[0][0] * V[0][0] + V[1][0] * V[0][1] + V[2][0] * V[0][2];
  const float M11 = V[0][1] * V[1][0] + V[1][1] * V[1][1] + V[2][1] * V[1][2];
  const float M22 = V[0][2] * V[2][0] + V[1][2] * V[2][1] + V[2][2] * V[2][2];

  const float T = S0 * M00 + S1 * M11 + dsg * S2 * M22;
  const float mse = (Sp + Sq - 2.f * T) * (1.f / (3.f * (float)N_));
  return sqrtf(mse + 1e-8f);
}

// ---------------------------------------------------------------------------
// Kernel 1: per-(b,k) moments + in-block svd -> rmsd[idx], plain store.
// 1280 blocks x 256 threads = 5 blocks/CU, 20 waves/CU; 17 thin accumulators.
// Block index idx = k*256 + b keeps all K=5 blocks of a given b on one XCD
// (idx%8 == b%8) for L2-local target re-reads (R2->R3: -6.7us).
// ---------------------------------------------------------------------------
__global__ __launch_bounds__(256) void kabsch_moments_svd(
    const float* __restrict__ preds, const float* __restrict__ target,
    float* __restrict__ rmsd) {
  const int idx = blockIdx.x;         // 0..1279, idx = k*256 + b
  const int b = idx & 255;
  const int k = idx >> 8;
  const int pair_orig = b * K_ + k;   // preds memory order is [B,K,N,3]
  const int tid = threadIdx.x;

  const float4* __restrict__ P4 =
      reinterpret_cast<const float4*>(preds) + (size_t)pair_orig * (N_ * 3 / 4);
  const float4* __restrict__ Q4 =
      reinterpret_cast<const float4*>(target) + (size_t)b * (N_ * 3 / 4);

  float acc[NMOM];
#pragma unroll
  for (int i = 0; i < NMOM; ++i) acc[i] = 0.f;

  // 4096 points = 1024 chunks of 4 points (3 float4 each); 256 threads x 4
#pragma unroll
  for (int j = 0; j < 4; ++j) {
    const int c = tid + j * 256;
    const float4 a0 = P4[3 * c + 0], a1 = P4[3 * c + 1], a2 = P4[3 * c + 2];
    const float4 b0 = Q4[3 * c + 0], b1 = Q4[3 * c + 1], b2 = Q4[3 * c + 2];
    const float p[4][3] = {{a0.x, a0.y, a0.z},
                           {a0.w, a1.x, a1.y},
                           {a1.z, a1.w, a2.x},
                           {a2.y, a2.z, a2.w}};
    const float q[4][3] = {{b0.x, b0.y, b0.z},
                           {b0.w, b1.x, b1.y},
                           {b1.z, b1.w, b2.x},
                           {b2.y, b2.z, b2.w}};
#pragma unroll
    for (int m = 0; m < 4; ++m) {
      const float px = p[m][0], py = p[m][1], pz = p[m][2];
      const float qx = q[m][0], qy = q[m][1], qz = q[m][2];
      acc[0] += px; acc[1] += py; acc[2] += pz;
      acc[3] += qx; acc[4] += qy; acc[5] += qz;
      acc[6] = fmaf(px, px, fmaf(py, py, fmaf(pz, pz, acc[6])));
      acc[7] = fmaf(qx, qx, fmaf(qy, qy, fmaf(qz, qz, acc[7])));
      acc[8]  = fmaf(px, qx, acc[8]);
      acc[9]  = fmaf(px, qy, acc[9]);
      acc[10] = fmaf(px, qz, acc[10]);
      acc[11] = fmaf(py, qx, acc[11]);
      acc[12] = fmaf(py, qy, acc[12]);
      acc[13] = fmaf(py, qz, acc[13]);
      acc[14] = fmaf(pz, qx, acc[14]);
      acc[15] = fmaf(pz, qy, acc[15]);
      acc[16] = fmaf(pz, qz, acc[16]);
    }
  }

  // wave64 butterfly reduce, then cross-wave via LDS
#pragma unroll
  for (int off = 32; off > 0; off >>= 1) {
#pragma unroll
    for (int i = 0; i < NMOM; ++i) acc[i] += __shfl_down(acc[i], off, 64);
  }

  __shared__ float red[4][NMOM];
  const int lane = tid & 63, wid = tid >> 6;
  if (lane == 0) {
#pragma unroll
    for (int i = 0; i < NMOM; ++i) red[wid][i] = acc[i];
  }
  __syncthreads();

  // in-block svd tail: ~1.5k-cycle f32 chain on lane 0, plain store, done.
  if (tid == 0) {
    float m[NMOM];
#pragma unroll
    for (int i = 0; i < NMOM; ++i)
      m[i] = red[0][i] + red[1][i] + red[2][i] + red[3][i];
    rmsd[idx] = svd_rmsd(m);
  }
}

// ---------------------------------------------------------------------------
// Kernel 2: min over K, mean over B -> scalar.
// rmsd layout is idx = k*256 + b, so per-b min reads stride-256 (coalesced).
// ---------------------------------------------------------------------------
__global__ __launch_bounds__(256) void kabsch_final(
    const float* __restrict__ rmsd, float* __restrict__ out) {
  const int b = threadIdx.x;  // 256 threads == B_
  float mn = rmsd[b];
#pragma unroll
  for (int k = 1; k < K_; ++k) mn = fminf(mn, rmsd[k * 256 + b]);
#pragma unroll
  for (int off = 32; off > 0; off >>= 1) mn += __shfl_down(mn, off, 64);
  __shared__ float s[4];
  if ((b & 63) == 0) s[b >> 6] = mn;
  __syncthreads();
  if (b == 0) out[0] = (s[0] + s[1] + s[2] + s[3]) * (1.0f / 256.0f);
}

extern "C" void kernel_launch(void* const* d_in, const int* in_sizes, int n_in,
                              void* d_out, int out_size, void* d_ws, size_t ws_size,
                              hipStream_t stream) {
  const float* preds = (const float*)d_in[0];
  const float* target = (const float*)d_in[1];
  float* out = (float*)d_out;
  float* rm = (float*)d_ws;                      // NPAIR floats

  hipLaunchKernelGGL(kabsch_moments_svd, dim3(NPAIR), dim3(256), 0, stream,
                     preds, target, rm);
  hipLaunchKernelGGL(kabsch_final, dim3(1), dim3(256), 0, stream, rm, out);
}